// Round 10
// baseline (164.196 us; speedup 1.0000x reference)
//
#include <hip/hip_runtime.h>

// ======================= DIAGNOSTIC ROUND =======================
// Exact R6 structure, but the fused kernel repeats its (idempotent) work
// NPASS times so its dispatch tops the rocprof table and we finally see
// FETCH_SIZE / WRITE_SIZE / VALUBusy / occupancy for the real kernel.
// Output is written identically each pass -> still correct.
// ================================================================

#define S_LEN 512
#define B_SZ  512
#define D_DIM 256
#define SEP_ID 13
#define PAD_ID 1

#define NTHR   256
#define ROWS_PER_WAVE 32
#define ROWS_PER_BLOCK 128
#define NROWS  (S_LEN * B_SZ)
#define NBLK   (NROWS / ROWS_PER_BLOCK)
#define NPASS  4

typedef float f32x4 __attribute__((ext_vector_type(4)));

// Kernel 1: wave-parallel inner-padding state machine (identical to R6).
__global__ void emb_scan_wave(const int* __restrict__ seq,
                              int* __restrict__ idx) {
    const int lane = threadIdx.x & 63;
    const int b = blockIdx.x * (blockDim.x >> 6) + (threadIdx.x >> 6);
    if (b >= B_SZ) return;

    const int s0 = lane * (S_LEN / 64);      // 8 positions per lane
    int toks[8];
#pragma unroll
    for (int k = 0; k < 8; ++k) toks[k] = seq[(s0 + k) * B_SZ + b];

    unsigned A = 0u, Bf = 1u;
#pragma unroll
    for (int k = 0; k < 8; ++k) {
        unsigned a  = (toks[k] == SEP_ID) ? 1u : 0u;
        unsigned bb = (toks[k] == PAD_ID) ? 1u : 0u;
        A  = a | (A & bb);
        Bf = Bf & bb;
    }

    unsigned incA = A, incB = Bf;
    for (int d = 1; d < 64; d <<= 1) {
        unsigned Al = __shfl_up(incA, d, 64);
        unsigned Bl = __shfl_up(incB, d, 64);
        if (lane >= d) {
            incA = incA | (Al & incB);
            incB = Bl & incB;
        }
    }
    unsigned pin = __shfl_up(incA, 1, 64);
    if (lane == 0) pin = 0u;

    unsigned p = pin, skipbits = 0u;
    int cnt = 0;
#pragma unroll
    for (int k = 0; k < 8; ++k) {
        unsigned a  = (toks[k] == SEP_ID) ? 1u : 0u;
        unsigned bb = (toks[k] == PAD_ID) ? 1u : 0u;
        unsigned skip = p & bb;
        skipbits |= skip << k;
        cnt += (int)skip;
        p = a | skip;
    }

    int pref = cnt;
    for (int d = 1; d < 64; d <<= 1) {
        int v = __shfl_up(pref, d, 64);
        if (lane >= d) pref += v;
    }
    pref -= cnt;

    int pad = pref;
#pragma unroll
    for (int k = 0; k < 8; ++k) {
        int s = s0 + k;
        unsigned skip = (skipbits >> k) & 1u;
        idx[s * B_SZ + b] = skip ? -1 : (s - pad);
        pad += (int)skip;
    }
}

// Kernel 2: R6 fused body x NPASS (idempotent repeat for counter visibility).
__global__ void __launch_bounds__(NTHR)
emb_fused_kernel(const int* __restrict__ seq,
                 const float* __restrict__ tw,
                 const float* __restrict__ pe,
                 const int* __restrict__ idx,
                 float* __restrict__ out) {
    const unsigned lane  = threadIdx.x & 63u;
    const unsigned wid_s = (unsigned)__builtin_amdgcn_readfirstlane(threadIdx.x >> 6);
    const unsigned row0  = blockIdx.x * ROWS_PER_BLOCK + wid_s * ROWS_PER_WAVE;
    const unsigned doff  = lane * 4u;

    const int* __restrict__ tokp  = seq + row0;
    const int* __restrict__ pidxp = idx + row0;
    float* orow = out + (size_t)row0 * D_DIM + doff;

    for (int pass = 0; pass < NPASS; ++pass) {
#pragma unroll 8
        for (int it = 0; it < ROWS_PER_WAVE; ++it) {
            const int tok  = tokp[it];    // uniform addr -> s_load
            const int pidx = pidxp[it];   // uniform addr -> s_load

            const f32x4 tv = *(const f32x4*)(tw + (size_t)tok * D_DIM + doff);
            const int   pc = (pidx < 0) ? 0 : pidx;
            const f32x4 pv = *(const f32x4*)(pe + (size_t)pc * D_DIM + doff);
            const float pm = (pidx < 0) ? 0.0f : 1.0f;

            f32x4 o = tv + pv * pm;
            *(f32x4*)(orow + (size_t)it * D_DIM) = o;
        }
        // Prevent dead-store elimination / cross-pass load hoisting so each
        // pass re-issues the full memory traffic (steady-state probe).
        asm volatile("" ::: "memory");
    }
}

extern "C" void kernel_launch(void* const* d_in, const int* in_sizes, int n_in,
                              void* d_out, int out_size, void* d_ws, size_t ws_size,
                              hipStream_t stream) {
    const int*   seq = (const int*)d_in[0];    // [S, B] int32
    const float* tw  = (const float*)d_in[1];  // [VOCAB, D] f32
    const float* pe  = (const float*)d_in[2];  // [MAX_LEN, D] f32
    float* out = (float*)d_out;                // [S, B, D] f32
    int*   idx = (int*)d_ws;                   // [S, B] int32 scratch (1 MiB)

    emb_scan_wave<<<dim3(B_SZ / 4), dim3(256), 0, stream>>>(seq, idx);
    emb_fused_kernel<<<dim3(NBLK), dim3(NTHR), 0, stream>>>(seq, tw, pe, idx, out);
}

// Round 11
// 95.210 us; speedup vs baseline: 1.7246x; 1.7246x over previous
//
#include <hip/hip_runtime.h>

// Problem constants (match reference file)
#define S_LEN 512
#define B_SZ  512
#define D_DIM 256
#define SEP_ID 13
#define PAD_ID 1

#define NTHR   256
#define ROWS_PER_WAVE 32
#define ROWS_PER_BLOCK 128                            // 4 waves x 32 rows, all same s
#define NROWS  (S_LEN * B_SZ)                         // 262144
#define NBLK   (NROWS / ROWS_PER_BLOCK)               // 2048 blocks

typedef float f32x4 __attribute__((ext_vector_type(4)));

// Kernel 1 (REBUILT): 2-level per-column scan with coalesced access.
// 8 blocks x 256 threads. Block owns 64 columns (lane = column). Wave w owns
// s-chunk [w*128, w*128+128). Pass 1: dual-state simulation (incoming
// prev_sep = 0 and = 1) + bitpacked sep/pad flags in registers. Chunk
// summaries compose through LDS. Pass 2: re-walk with true incoming state,
// coalesced 256B stores of idx.
__global__ void __launch_bounds__(256)
emb_scan_2level(const int* __restrict__ seq, int* __restrict__ idx) {
    const int lane = threadIdx.x & 63;
    const int w    = threadIdx.x >> 6;            // chunk 0..3
    const int col  = blockIdx.x * 64 + lane;      // 0..511
    const int sbase = w * 128;

    __shared__ unsigned summ[4][64];

    // ---- Pass 1: dual-state simulation + flag bitpack (coalesced loads) ----
    unsigned sepb[4], padb[4];
    unsigned p0 = 0u, p1 = 1u, c0 = 0u, c1 = 0u;
#pragma unroll
    for (int q = 0; q < 4; ++q) {                 // compile-time dword index
        unsigned sb = 0u, pb = 0u;
#pragma unroll
        for (int j = 0; j < 32; ++j) {
            const int t = seq[(sbase + q * 32 + j) * B_SZ + col];
            const unsigned is_sep = (t == SEP_ID) ? 1u : 0u;
            const unsigned is_pad = (t == PAD_ID) ? 1u : 0u;
            sb |= is_sep << j;
            pb |= is_pad << j;
            const unsigned k0 = p0 & is_pad; c0 += k0; p0 = is_sep | k0;
            const unsigned k1 = p1 & is_pad; c1 += k1; p1 = is_sep | k1;
        }
        sepb[q] = sb;
        padb[q] = pb;
    }
    // Pack: p_out(0) bit0, p_out(1) bit1, c0 bits[8:20), c1 bits[20:32)
    summ[w][lane] = p0 | (p1 << 1) | (c0 << 8) | (c1 << 20);
    __syncthreads();

    // ---- Compose incoming state for this wave's chunk (serial over w) ----
    unsigned p = 0u, padn = 0u;
    for (int ww = 0; ww < w; ++ww) {              // wave-uniform trip count
        const unsigned sm = summ[ww][lane];
        padn += p ? ((sm >> 20) & 0xFFFu) : ((sm >> 8) & 0xFFFu);
        p = p ? ((sm >> 1) & 1u) : (sm & 1u);
    }

    // ---- Pass 2: walk with true state, coalesced stores ----
#pragma unroll
    for (int q = 0; q < 4; ++q) {
        const unsigned sb = sepb[q];
        const unsigned pb = padb[q];
#pragma unroll
        for (int j = 0; j < 32; ++j) {
            const unsigned is_sep = (sb >> j) & 1u;
            const unsigned is_pad = (pb >> j) & 1u;
            const unsigned sk = p & is_pad;
            const int s = sbase + q * 32 + j;
            idx[s * B_SZ + col] = sk ? -1 : (int)(s - padn);
            padn += sk;
            p = is_sep | sk;
        }
    }
}

// Kernel 2: fused gather+add — byte-identical to R6 (best: 53.4 us).
__global__ void __launch_bounds__(NTHR)
emb_fused_kernel(const int* __restrict__ seq,
                 const float* __restrict__ tw,
                 const float* __restrict__ pe,
                 const int* __restrict__ idx,
                 float* __restrict__ out) {
    const unsigned lane  = threadIdx.x & 63u;
    const unsigned wid_s = (unsigned)__builtin_amdgcn_readfirstlane(threadIdx.x >> 6);
    const unsigned row0  = blockIdx.x * ROWS_PER_BLOCK + wid_s * ROWS_PER_WAVE;
    const unsigned doff  = lane * 4u;

    const int* __restrict__ tokp  = seq + row0;   // wave-uniform pointers
    const int* __restrict__ pidxp = idx + row0;
    float* orow = out + (size_t)row0 * D_DIM + doff;

#pragma unroll 8
    for (int it = 0; it < ROWS_PER_WAVE; ++it) {
        const int tok  = tokp[it];    // uniform addr -> s_load
        const int pidx = pidxp[it];   // uniform addr -> s_load

        const f32x4 tv = *(const f32x4*)(tw + (size_t)tok * D_DIM + doff);
        const int   pc = (pidx < 0) ? 0 : pidx;
        const f32x4 pv = *(const f32x4*)(pe + (size_t)pc * D_DIM + doff);
        const float pm = (pidx < 0) ? 0.0f : 1.0f;

        f32x4 o = tv + pv * pm;
        *(f32x4*)(orow + (size_t)it * D_DIM) = o;
    }
}

extern "C" void kernel_launch(void* const* d_in, const int* in_sizes, int n_in,
                              void* d_out, int out_size, void* d_ws, size_t ws_size,
                              hipStream_t stream) {
    const int*   seq = (const int*)d_in[0];    // [S, B] int32
    const float* tw  = (const float*)d_in[1];  // [VOCAB, D] f32
    const float* pe  = (const float*)d_in[2];  // [MAX_LEN, D] f32
    float* out = (float*)d_out;                // [S, B, D] f32
    int*   idx = (int*)d_ws;                   // [S, B] int32 scratch (1 MiB)

    // 1) 2-level coalesced scan: 8 blocks x 256 threads, 64 columns each
    emb_scan_2level<<<dim3(B_SZ / 64), dim3(256), 0, stream>>>(seq, idx);

    // 2) fused gather+add: 2048 blocks x 256, 128 contiguous rows per block
    emb_fused_kernel<<<dim3(NBLK), dim3(NTHR), 0, stream>>>(seq, tw, pe, idx, out);
}

// Round 12
// 53.109 us; speedup vs baseline: 3.0917x; 1.7927x over previous
//
#include <hip/hip_runtime.h>

// Problem constants (match reference file)
#define S_LEN 512
#define B_SZ  512
#define D_DIM 256
#define SEP_ID 13
#define PAD_ID 1

#define NTHR   256
#define ROWS_PER_WAVE 32
#define ROWS_PER_BLOCK 128                            // 4 waves x 32 rows
#define NROWS  (S_LEN * B_SZ)                         // 262144
#define NBLK_P 512                                    // persistent-ish grid
#define CHUNKS (NROWS / (NBLK_P * ROWS_PER_BLOCK))    // 4 sequential chunks

typedef float f32x4 __attribute__((ext_vector_type(4)));

// Kernel 1: wave-parallel inner-padding state machine (R6 proven version).
__global__ void emb_scan_wave(const int* __restrict__ seq,
                              int* __restrict__ idx) {
    const int lane = threadIdx.x & 63;
    const int b = blockIdx.x * (blockDim.x >> 6) + (threadIdx.x >> 6);
    if (b >= B_SZ) return;

    const int s0 = lane * (S_LEN / 64);      // 8 positions per lane
    int toks[8];
#pragma unroll
    for (int k = 0; k < 8; ++k) toks[k] = seq[(s0 + k) * B_SZ + b];

    // Local transfer function over this lane's 8 tokens: f(p) = A | (p & B)
    unsigned A = 0u, Bf = 1u;
#pragma unroll
    for (int k = 0; k < 8; ++k) {
        unsigned a  = (toks[k] == SEP_ID) ? 1u : 0u;
        unsigned bb = (toks[k] == PAD_ID) ? 1u : 0u;
        A  = a | (A & bb);
        Bf = Bf & bb;
    }

    // Inclusive Kogge-Stone scan of function composition (lower lanes first)
    unsigned incA = A, incB = Bf;
    for (int d = 1; d < 64; d <<= 1) {
        unsigned Al = __shfl_up(incA, d, 64);
        unsigned Bl = __shfl_up(incB, d, 64);
        if (lane >= d) {
            incA = incA | (Al & incB);
            incB = Bl & incB;
        }
    }
    unsigned pin = __shfl_up(incA, 1, 64);
    if (lane == 0) pin = 0u;

    // Recompute the 8 steps with the true incoming state
    unsigned p = pin, skipbits = 0u;
    int cnt = 0;
#pragma unroll
    for (int k = 0; k < 8; ++k) {
        unsigned a  = (toks[k] == SEP_ID) ? 1u : 0u;
        unsigned bb = (toks[k] == PAD_ID) ? 1u : 0u;
        unsigned skip = p & bb;
        skipbits |= skip << k;
        cnt += (int)skip;
        p = a | skip;
    }

    // Exclusive prefix sum of per-lane skip counts -> pad_num at lane start
    int pref = cnt;
    for (int d = 1; d < 64; d <<= 1) {
        int v = __shfl_up(pref, d, 64);
        if (lane >= d) pref += v;
    }
    pref -= cnt;

    int pad = pref;
#pragma unroll
    for (int k = 0; k < 8; ++k) {
        int s = s0 + k;
        unsigned skip = (skipbits >> k) & 1u;
        idx[s * B_SZ + b] = skip ? -1 : (s - pad);
        pad += (int)skip;
    }
}

// Kernel 2: fused gather+add — R6 body, quasi-persistent: each block runs
// 4 sequential chunks (grid-stride) so chunks 2-4 execute with warm
// tables/TLB/write path (the regime R10 showed runs at fill rate).
__global__ void __launch_bounds__(NTHR)
emb_fused_kernel(const int* __restrict__ seq,
                 const float* __restrict__ tw,
                 const float* __restrict__ pe,
                 const int* __restrict__ idx,
                 float* __restrict__ out) {
    const unsigned lane  = threadIdx.x & 63u;
    const unsigned wid_s = (unsigned)__builtin_amdgcn_readfirstlane(threadIdx.x >> 6);
    const unsigned doff  = lane * 4u;

    for (unsigned c = 0; c < CHUNKS; ++c) {
        const unsigned row0 = (c * NBLK_P + blockIdx.x) * ROWS_PER_BLOCK
                              + wid_s * ROWS_PER_WAVE;

        const int* __restrict__ tokp  = seq + row0;   // wave-uniform pointers
        const int* __restrict__ pidxp = idx + row0;
        float* orow = out + (size_t)row0 * D_DIM + doff;

#pragma unroll 8
        for (int it = 0; it < ROWS_PER_WAVE; ++it) {
            const int tok  = tokp[it];    // uniform addr -> s_load
            const int pidx = pidxp[it];   // uniform addr -> s_load

            const f32x4 tv = *(const f32x4*)(tw + (size_t)tok * D_DIM + doff);
            const int   pc = (pidx < 0) ? 0 : pidx;
            const f32x4 pv = *(const f32x4*)(pe + (size_t)pc * D_DIM + doff);
            const float pm = (pidx < 0) ? 0.0f : 1.0f;

            f32x4 o = tv + pv * pm;
            *(f32x4*)(orow + (size_t)it * D_DIM) = o;
        }
    }
}

extern "C" void kernel_launch(void* const* d_in, const int* in_sizes, int n_in,
                              void* d_out, int out_size, void* d_ws, size_t ws_size,
                              hipStream_t stream) {
    const int*   seq = (const int*)d_in[0];    // [S, B] int32
    const float* tw  = (const float*)d_in[1];  // [VOCAB, D] f32
    const float* pe  = (const float*)d_in[2];  // [MAX_LEN, D] f32
    float* out = (float*)d_out;                // [S, B, D] f32
    int*   idx = (int*)d_ws;                   // [S, B] int32 scratch (1 MiB)

    // 1) wave-parallel scan: 512 columns, 1 wave each -> 128 blocks x 256
    emb_scan_wave<<<dim3(B_SZ / 4), dim3(256), 0, stream>>>(seq, idx);

    // 2) fused gather+add: 512 blocks x 4 chunks, warm after chunk 1
    emb_fused_kernel<<<dim3(NBLK_P), dim3(NTHR), 0, stream>>>(seq, tw, pe, idx, out);
}